// Round 1
// 198.839 us; speedup vs baseline: 1.0078x; 1.0078x over previous
//
#include <hip/hip_runtime.h>
#include <hip/hip_bf16.h>
#include <hip/hip_fp8.h>
#include <hip/hip_fp16.h>

#define N_NODESC 100000
#define N_EDGESC 1600000
#define FEATC 64
#define HEADSC 8
#define BATCHC 64
#define MAXLENC 2048
#define NBUCK 500          // 500 buckets x exactly 200 dst nodes
#define BSZ 200
#define CAP 6144           // LDS edge capacity per bucket (mean 3200, sigma ~57)
#define P3_EDGES 8192      // edges per k_csort workgroup (1024 thr x 8)
#define K1B 391            // k_pre blocks doing the node transform

typedef float f32x2 __attribute__((ext_vector_type(2)));

__device__ __forceinline__ float b2f(unsigned short u){
  union { unsigned u; float f; } c; c.u = ((unsigned)u) << 16; return c.f;
}
__device__ __forceinline__ unsigned short f2b(float f){
  union { float f; unsigned u; } c; c.f = f;
  unsigned r = c.u + 0x7fffu + ((c.u >> 16) & 1u);
  return (unsigned short)(r >> 16);
}
__device__ __forceinline__ int clampi(int v, int lo, int hi){
  return v < lo ? lo : (v > hi ? hi : v);
}
__device__ __forceinline__ void unpack8(uint4 v, float* o){
  o[0] = b2f((unsigned short)(v.x & 0xffff)); o[1] = b2f((unsigned short)(v.x >> 16));
  o[2] = b2f((unsigned short)(v.y & 0xffff)); o[3] = b2f((unsigned short)(v.y >> 16));
  o[4] = b2f((unsigned short)(v.z & 0xffff)); o[5] = b2f((unsigned short)(v.z >> 16));
  o[6] = b2f((unsigned short)(v.w & 0xffff)); o[7] = b2f((unsigned short)(v.w >> 16));
}
__device__ __forceinline__ float fp8tof(unsigned char b){
  __hip_fp8_e4m3 q; q.__x = (__hip_fp8_storage_t)b; return (float)q;
}
// 4 x fp8(e4m3, OCP on gfx950) packed in a dword -> 4 floats via v_cvt_pk_f32_fp8
__device__ __forceinline__ void cvt4(unsigned v, float* o){
  f32x2 lo = __builtin_amdgcn_cvt_pk_f32_fp8((int)v, false);
  f32x2 hi = __builtin_amdgcn_cvt_pk_f32_fp8((int)v, true);
  o[0] = lo.x; o[1] = lo.y; o[2] = hi.x; o[3] = hi.y;
}

// ---- K_pre: heterogeneous grid. Blocks [0,K1B): xw=x@W -> fp8 + a_src(fp16)
// + a_dst(fp32). Blocks [K1B,..): coarse 500-bin histogram of dst. ----
__global__ __launch_bounds__(256) void k_pre(
    const unsigned short* __restrict__ x, const unsigned short* __restrict__ W,
    const unsigned short* __restrict__ attS, const unsigned short* __restrict__ attD,
    const int* __restrict__ ei,
    unsigned char* __restrict__ xw8, __half* __restrict__ a_srch,
    float* __restrict__ a_dst, int* __restrict__ cc)
{
  __shared__ float Wsf[64 * 64];
  __shared__ float as_s[64];
  __shared__ float ad_s[64];
  __shared__ int hh[NBUCK];
  int t = threadIdx.x;

  if (blockIdx.x >= K1B) {
    // ---- coarse histogram part ----
    for (int i = t; i < NBUCK; i += 256) hh[i] = 0;
    __syncthreads();
    int g = (blockIdx.x - K1B) * 256 + t;
    if (g < N_EDGESC / 4) {
      int4 d = ((const int4*)(ei + N_EDGESC))[g];
      atomicAdd(&hh[clampi(d.x, 0, N_NODESC - 1) / BSZ], 1);
      atomicAdd(&hh[clampi(d.y, 0, N_NODESC - 1) / BSZ], 1);
      atomicAdd(&hh[clampi(d.z, 0, N_NODESC - 1) / BSZ], 1);
      atomicAdd(&hh[clampi(d.w, 0, N_NODESC - 1) / BSZ], 1);
    }
    __syncthreads();
    for (int i = t; i < NBUCK; i += 256) if (hh[i]) atomicAdd(&cc[i], hh[i]);
    return;
  }

  // ---- node transform part ----
  for (int i = t; i < 4096; i += 256) Wsf[i] = b2f(W[i]);
  if (t < 64) { as_s[t] = b2f(attS[t]); ad_s[t] = b2f(attD[t]); }
  __syncthreads();

  int g    = t & 3;
  int slot = t >> 2;
  int n0 = blockIdx.x * 256 + slot * 4;

  float acc[4][16];
  #pragma unroll
  for (int j = 0; j < 4; j++)
    #pragma unroll
    for (int c = 0; c < 16; c++) acc[j][c] = 0.f;

  const float4* Ws4 = (const float4*)Wsf;
  for (int i = 0; i < 8; i++) {
    float xu[4][8];
    #pragma unroll
    for (int j = 0; j < 4; j++) {
      int n = n0 + j;
      uint4 v = make_uint4(0u,0u,0u,0u);
      if (n < N_NODESC) v = ((const uint4*)(x + (size_t)n * 64))[i];
      unpack8(v, xu[j]);
    }
    #pragma unroll
    for (int u = 0; u < 8; u++) {
      int k = i * 8 + u;
      float4 w0 = Ws4[k * 16 + g * 4 + 0];
      float4 w1 = Ws4[k * 16 + g * 4 + 1];
      float4 w2 = Ws4[k * 16 + g * 4 + 2];
      float4 w3 = Ws4[k * 16 + g * 4 + 3];
      #pragma unroll
      for (int j = 0; j < 4; j++) {
        float xk = xu[j][u];
        acc[j][ 0] += xk * w0.x; acc[j][ 1] += xk * w0.y;
        acc[j][ 2] += xk * w0.z; acc[j][ 3] += xk * w0.w;
        acc[j][ 4] += xk * w1.x; acc[j][ 5] += xk * w1.y;
        acc[j][ 6] += xk * w1.z; acc[j][ 7] += xk * w1.w;
        acc[j][ 8] += xk * w2.x; acc[j][ 9] += xk * w2.y;
        acc[j][10] += xk * w2.z; acc[j][11] += xk * w2.w;
        acc[j][12] += xk * w3.x; acc[j][13] += xk * w3.y;
        acc[j][14] += xk * w3.z; acc[j][15] += xk * w3.w;
      }
    }
  }

  #pragma unroll
  for (int j = 0; j < 4; j++) {
    int n = n0 + j;
    if (n >= N_NODESC) break;
    union { unsigned u[4]; unsigned char b[16]; } pk;
    #pragma unroll
    for (int c = 0; c < 16; c++)
      pk.b[c] = (unsigned char)__hip_fp8_e4m3(acc[j][c]).__x;
    uint4 o; o.x = pk.u[0]; o.y = pk.u[1]; o.z = pk.u[2]; o.w = pk.u[3];
    *((uint4*)(xw8 + (size_t)n * 64 + g * 16)) = o;

    #pragma unroll
    for (int hl = 0; hl < 2; hl++) {
      int h = g * 2 + hl;
      float sa = 0.f, sd = 0.f;
      #pragma unroll
      for (int c = 0; c < 8; c++) {
        sa += acc[j][hl * 8 + c] * as_s[h * 8 + c];
        sd += acc[j][hl * 8 + c] * ad_s[h * 8 + c];
      }
      a_srch[n * 8 + h] = __float2half(sa);
      a_dst[n * 8 + h] = sd;
    }
  }
}

// ---- coarse scatter (1024 thr, 8192 edges/wg): self-scan of cc -> bstart,
// LDS counting-sort by bucket, contiguous run writes via zero-based gcur ----
__global__ __launch_bounds__(1024) void k_csort(const int* __restrict__ ei,
                                                const int* __restrict__ cc,
                                                int* __restrict__ gcur,
                                                unsigned* __restrict__ cs) {
  __shared__ int bst[512];
  __shared__ int h[NBUCK], lst[NBUCK], lcur[NBUCK], gb[NBUCK];
  __shared__ int sc[512];
  __shared__ unsigned sorted[P3_EDGES];
  __shared__ unsigned short sbk[P3_EDGES];
  int t = threadIdx.x;
  int base = blockIdx.x * P3_EDGES;
  for (int i = t; i < NBUCK; i += 1024) h[i] = 0;
  int myc = 0;
  if (t < 512) { myc = (t < NBUCK) ? cc[t] : 0; bst[t] = myc; }
  __syncthreads();
  for (int off = 1; off < 512; off <<= 1) {
    int v = 0;
    if (t < 512) { v = bst[t]; if (t >= off) v += bst[t - off]; }
    __syncthreads();
    if (t < 512) bst[t] = v;
    __syncthreads();
  }
  unsigned pk[8]; int bk[8];
  #pragma unroll
  for (int k = 0; k < 8; k++) {
    int idx = base + k * 1024 + t;
    bk[k] = -1;
    if (idx < N_EDGESC) {
      int s = clampi(ei[idx], 0, N_NODESC - 1);
      int d = clampi(ei[N_EDGESC + idx], 0, N_NODESC - 1);
      int b = d / BSZ;
      pk[k] = (unsigned)s | ((unsigned)(d - b * BSZ) << 17);
      bk[k] = b;
      atomicAdd(&h[b], 1);
    }
  }
  __syncthreads();
  if (t < 512) sc[t] = (t < NBUCK) ? h[t] : 0;
  __syncthreads();
  for (int off = 1; off < 512; off <<= 1) {
    int v = 0;
    if (t < 512) { v = sc[t]; if (t >= off) v += sc[t - off]; }
    __syncthreads();
    if (t < 512) sc[t] = v;
    __syncthreads();
  }
  if (t < NBUCK) {
    int ex = sc[t] - h[t];
    lst[t] = ex; lcur[t] = ex;
    if (h[t]) gb[t] = (bst[t] - myc) + atomicAdd(&gcur[t], h[t]);
  }
  __syncthreads();
  #pragma unroll
  for (int k = 0; k < 8; k++) if (bk[k] >= 0) {
    int p = atomicAdd(&lcur[bk[k]], 1);
    sorted[p] = pk[k];
    sbk[p] = (unsigned short)bk[k];
  }
  __syncthreads();
  int cnt = N_EDGESC - base; if (cnt > P3_EDGES) cnt = P3_EDGES;
  #pragma unroll
  for (int k = 0; k < 8; k++) {
    int i = k * 1024 + t;
    if (i < cnt) {
      int b = sbk[i];
      cs[gb[b] + (i - lst[b])] = sorted[i];
    }
  }
}

// ---- K_aggf: one 1024-thread WG per bucket (200 dsts). Self-scans cc for
// its base; counting-sorts its edges into LDS (cs entries cached in regs);
// per-dst wave aggregation.
// v2 edge loop: lane l = stripe g=l>>4 x channel-quad k=l&15 (channels 4k..4k+3,
// head h2=k>>1). One global_load_dword per 4 edges + v_cvt_pk_f32_fp8 decode +
// one ds_bpermute alpha-broadcast per 4 edges; 1-deep software pipeline keeps
// the next group's ssrc/a_src/xw8 loads in flight under the current FMAs.
// (old version: 8 serialized ubyte gathers per group -> latency-bound, VGPR=28.)
__global__ __launch_bounds__(1024) void k_aggf(
    const __half* __restrict__ a_srch, const float* __restrict__ a_dst,
    const unsigned char* __restrict__ xw8, const unsigned* __restrict__ cs,
    const int* __restrict__ cc,
    const unsigned short* __restrict__ bias, unsigned short* __restrict__ nembh)
{
  __shared__ int bsc[512];
  __shared__ int lcnt[256], loff[256], lcur[256];
  __shared__ int ssrc[CAP];
  __shared__ int sbase, scnt0;
  int t = threadIdx.x;
  int b = blockIdx.x;

  int myc = 0;
  if (t < 512) { myc = (t < NBUCK) ? cc[t] : 0; bsc[t] = myc; }
  __syncthreads();
  for (int off = 1; off < 512; off <<= 1) {
    int v = 0;
    if (t < 512) { v = bsc[t]; if (t >= off) v += bsc[t - off]; }
    __syncthreads();
    if (t < 512) bsc[t] = v;
    __syncthreads();
  }
  if (t == b) { sbase = bsc[t] - myc; scnt0 = myc; }
  if (t < 256) lcnt[t] = 0;
  __syncthreads();
  int base = sbase;
  int cnt  = scnt0;
  int scnt = cnt < CAP ? cnt : CAP;

  unsigned ce[6];
  #pragma unroll
  for (int j = 0; j < 6; j++) {
    int i = t + j * 1024;
    if (i < scnt) { ce[j] = cs[base + i]; atomicAdd(&lcnt[ce[j] >> 17], 1); }
  }
  __syncthreads();
  if (t < 256) loff[t] = lcnt[t];
  __syncthreads();
  for (int off = 1; off < 256; off <<= 1) {
    int v = 0;
    if (t < 256) { v = loff[t]; if (t >= off) v += loff[t - off]; }
    __syncthreads();
    if (t < 256) loff[t] = v;
    __syncthreads();
  }
  if (t < 256) { int ex = loff[t] - lcnt[t]; loff[t] = ex; lcur[t] = ex; }
  __syncthreads();
  #pragma unroll
  for (int j = 0; j < 6; j++) {
    int i = t + j * 1024;
    if (i < scnt) {
      int p = atomicAdd(&lcur[ce[j] >> 17], 1);
      ssrc[p] = (int)(ce[j] & 0x1FFFFu);
    }
  }
  __syncthreads();

  int wv = t >> 6;
  int l  = t & 63;
  int H  = l >> 3;        // edge offset within 8-group (w-producer role)
  int hw = l & 7;         // head (w-producer role): w(edge H, head hw) lives in lane H*8+hw
  int k  = l & 15;        // channel quad: channels 4k..4k+3
  int g  = l >> 4;        // edge stripe (0..3)
  int h2 = k >> 1;        // head owning channels 4k..4k+3

  // byte addrs into the wave for ds_bpermute alpha-broadcast: lane (edge*8+h2)*4
  int bp0 = ((g << 3) | h2) << 2;          // step 0: edge g
  int bp1 = (((g + 4) << 3) | h2) << 2;    // step 1: edge 4+g

  uint2 bb = ((const uint2*)bias)[k];
  float bs0 = b2f((unsigned short)(bb.x & 0xffff));
  float bs1 = b2f((unsigned short)(bb.x >> 16));
  float bs2 = b2f((unsigned short)(bb.y & 0xffff));
  float bs3 = b2f((unsigned short)(bb.y >> 16));

  for (int dl = wv; dl < BSZ; dl += 16) {
    int dst = b * BSZ + dl;
    float adW = a_dst[dst * 8 + hw];                     // for edge alphas
    float adA = a_dst[dst * 8 + h2];                     // for self / overflow
    float zs  = __half2float(a_srch[dst * 8 + h2]) + adA;
    float selfw = __expf(fmaxf(zs, 0.2f * zs));

    // self edge: only stripe 0 contributes (reduced across stripes later)
    unsigned sd = *(const unsigned*)(xw8 + (size_t)dst * 64 + (k << 2));
    float sx[4]; cvt4(sd, sx);
    float sw = (g == 0) ? selfw : 0.f;
    float a0 = sw * sx[0], a1 = sw * sx[1], a2 = sw * sx[2], a3 = sw * sx[3];

    int beg  = loff[dl];
    int deg  = lcnt[dl];
    int end2 = beg + deg;
    float lw = 0.f;

    if (deg > 0) {
      int last = end2 - 1;
      // prologue: prefetch group 0
      int iw = beg + H; if (iw > last) iw = last;
      float av = __half2float(a_srch[ssrc[iw] * 8 + hw]);
      int e0 = beg + g;     if (e0 > last) e0 = last;
      int e1 = beg + 4 + g; if (e1 > last) e1 = last;
      unsigned d0 = *(const unsigned*)(xw8 + (size_t)ssrc[e0] * 64 + (k << 2));
      unsigned d1 = *(const unsigned*)(xw8 + (size_t)ssrc[e1] * 64 + (k << 2));

      for (int i = beg; i < end2; i += 8) {
        // current group's alpha (lane = edge H, head hw)
        float z = av + adW;
        float w = __expf(fmaxf(z, 0.2f * z));
        w = (i + H < end2) ? w : 0.f;
        lw += w;
        unsigned c0 = d0, c1 = d1;
        // prefetch next group while FMAs below consume the current one
        int nx = i + 8;
        if (nx < end2) {
          int iw2 = nx + H; if (iw2 > last) iw2 = last;
          av = __half2float(a_srch[ssrc[iw2] * 8 + hw]);
          int f0 = nx + g;     if (f0 > last) f0 = last;
          int f1 = nx + 4 + g; if (f1 > last) f1 = last;
          d0 = *(const unsigned*)(xw8 + (size_t)ssrc[f0] * 64 + (k << 2));
          d1 = *(const unsigned*)(xw8 + (size_t)ssrc[f1] * 64 + (k << 2));
        }
        // broadcast alpha for (edge g / 4+g, head h2) and accumulate 4 channels
        int wi = __float_as_int(w);
        float w0 = __int_as_float(__builtin_amdgcn_ds_bpermute(bp0, wi));
        float w1 = __int_as_float(__builtin_amdgcn_ds_bpermute(bp1, wi));
        float x0[4]; cvt4(c0, x0);
        a0 += w0 * x0[0]; a1 += w0 * x0[1]; a2 += w0 * x0[2]; a3 += w0 * x0[3];
        float x1[4]; cvt4(c1, x1);
        a0 += w1 * x1[0]; a1 += w1 * x1[1]; a2 += w1 * x1[2]; a3 += w1 * x1[3];
      }
    }

    // reduce partial sums across the 4 edge stripes
    a0 += __shfl_xor(a0, 16, 64); a0 += __shfl_xor(a0, 32, 64);
    a1 += __shfl_xor(a1, 16, 64); a1 += __shfl_xor(a1, 32, 64);
    a2 += __shfl_xor(a2, 16, 64); a2 += __shfl_xor(a2, 32, 64);
    a3 += __shfl_xor(a3, 16, 64); a3 += __shfl_xor(a3, 32, 64);
    lw += __shfl_xor(lw, 8, 64);
    lw += __shfl_xor(lw, 16, 64);
    lw += __shfl_xor(lw, 32, 64);
    float dsum = __shfl(lw, h2, 64);     // full per-head edge sum

    // overflow edges beyond LDS capacity (statistically never taken);
    // acc is fully reduced here, so every lane adds identically.
    float lw2 = 0.f;
    for (int i = CAP; i < cnt; i++) {
      unsigned e = cs[base + i];
      if ((int)(e >> 17) != dl) continue;
      int sv = (int)(e & 0x1FFFFu);
      float z = __half2float(a_srch[sv * 8 + h2]) + adA;
      float w = __expf(fmaxf(z, 0.2f * z));
      lw2 += w;
      unsigned dv = *(const unsigned*)(xw8 + (size_t)sv * 64 + (k << 2));
      float xo[4]; cvt4(dv, xo);
      a0 += w * xo[0]; a1 += w * xo[1]; a2 += w * xo[2]; a3 += w * xo[3];
    }

    float denom = selfw + dsum + lw2;
    if (l < 16) {
      float inv = __builtin_amdgcn_rcpf(denom);
      float v0 = a0 * inv + bs0; v0 = v0 > 0.f ? v0 : 0.f;
      float v1 = a1 * inv + bs1; v1 = v1 > 0.f ? v1 : 0.f;
      float v2 = a2 * inv + bs2; v2 = v2 > 0.f ? v2 : 0.f;
      float v3 = a3 * inv + bs3; v3 = v3 > 0.f ? v3 : 0.f;
      uint2 o;
      o.x = (unsigned)f2b(v0) | ((unsigned)f2b(v1) << 16);
      o.y = (unsigned)f2b(v2) | ((unsigned)f2b(v3) << 16);
      ((uint2*)nembh)[(size_t)dst * 16 + k] = o;
    }
  }
}

// ---- K6: padded gather from bf16 nemb -> fp32 out + seq_lengths tail ----
__global__ __launch_bounds__(256) void k6_gather(
    const unsigned short* __restrict__ nembh, const int* __restrict__ traj,
    const int* __restrict__ lens, float* __restrict__ out)
{
  int gid = blockIdx.x * 256 + threadIdx.x;
  if (gid < BATCHC * MAXLENC * 16) {
    int b = gid >> 15;
    int rem = gid & 32767;
    int l = rem >> 4;
    int ch = rem & 15;
    int len = clampi(lens[b], 0, MAXLENC);
    float4 val = make_float4(0.f, 0.f, 0.f, 0.f);
    if (l < len) {
      int node = clampi(traj[b * MAXLENC + l], 0, N_NODESC - 1);
      uint2 q = ((const uint2*)nembh)[(size_t)node * 16 + ch];
      val = make_float4(b2f((unsigned short)(q.x & 0xffff)),
                        b2f((unsigned short)(q.x >> 16)),
                        b2f((unsigned short)(q.y & 0xffff)),
                        b2f((unsigned short)(q.y >> 16)));
    }
    ((float4*)out)[gid] = val;
  }
  if (gid < BATCHC) {
    out[(size_t)BATCHC * MAXLENC * FEATC + gid] = (float)lens[gid];
  }
}

extern "C" void kernel_launch(void* const* d_in, const int* in_sizes, int n_in,
                              void* d_out, int out_size, void* d_ws, size_t ws_size,
                              hipStream_t stream) {
  const unsigned short* x    = (const unsigned short*)d_in[0];
  const unsigned short* W    = (const unsigned short*)d_in[1];
  const unsigned short* attS = (const unsigned short*)d_in[2];
  const unsigned short* attD = (const unsigned short*)d_in[3];
  const unsigned short* bias = (const unsigned short*)d_in[4];
  const int* ei   = (const int*)d_in[5];
  const int* traj = (const int*)d_in[6];
  const int* lens = (const int*)d_in[7];
  float* out = (float*)d_out;

  // workspace (float units, max 9.9M floats = 39.6 MB; under proven size):
  //  [0, 1.6M)        xw fp8 (6.4M bytes)
  //  [3.2M, 3.6M)     a_src fp16 (800k half)
  //  [4.0M, 4.8M)     a_dst fp32
  //  [4.9M, +512)     ccounts (500)
  //  [+512, +1024)    gcur (500, zero-based)   -- one memset covers both
  //  [5.0M, 6.6M)     cs (packed uint, 1.6M)
  //  [6.7M, 9.9M)     nemb bf16 (6.4M ushort)
  float* F = (float*)d_ws;
  unsigned char* xw8 = (unsigned char*)d_ws;
  __half* a_srch = (__half*)(F + 3200000);
  float* a_dst   = F + 4000000;
  int* ccounts   = (int*)(F + 4900000);
  int* gcur      = (int*)(F + 4900000) + 512;
  unsigned* cs   = (unsigned*)(F + 5000000);
  unsigned short* nembh = (unsigned short*)(F + 6700000);

  hipMemsetAsync(ccounts, 0, 1024 * sizeof(int), stream);
  k_pre<<<K1B + (N_EDGESC / 4 + 255) / 256, 256, 0, stream>>>(
      x, W, attS, attD, ei, xw8, a_srch, a_dst, ccounts);
  k_csort<<<(N_EDGESC + P3_EDGES - 1) / P3_EDGES, 1024, 0, stream>>>(ei, ccounts, gcur, cs);
  k_aggf<<<NBUCK, 1024, 0, stream>>>(a_srch, a_dst, xw8, cs, ccounts, bias, nembh);
  k6_gather<<<(BATCHC * MAXLENC * 16 + 255) / 256, 256, 0, stream>>>(nembh, traj, lens, out);
}